// Round 2
// baseline (649.360 us; speedup 1.0000x reference)
//
#include <hip/hip_runtime.h>
#include <hip/hip_bf16.h>
#include <math.h>

#define NTOK 32768
#define MCB  4096
#define DDIM 256

typedef __attribute__((ext_vector_type(8))) short bf16x8;
typedef __attribute__((ext_vector_type(4))) float f32x4;

__device__ __forceinline__ unsigned short f2bf_rne(float f) {
  unsigned int u = __float_as_uint(f);
  unsigned int r = u + 0x7FFFu + ((u >> 16) & 1u);
  return (unsigned short)(r >> 16);
}

__device__ __forceinline__ float bf2f(unsigned short h) {
  return __uint_as_float(((unsigned int)h) << 16);
}

__device__ __forceinline__ void cvt8(const float* f, bf16x8& hi, bf16x8& lo) {
  #pragma unroll
  for (int j = 0; j < 8; ++j) {
    unsigned short hs = f2bf_rne(f[j]);
    float lf = f[j] - bf2f(hs);
    hi[j] = (short)hs;
    lo[j] = (short)f2bf_rne(lf);
  }
}

__device__ __forceinline__ void load_lds16(const void* g, void* l) {
  __builtin_amdgcn_global_load_lds(
      (const __attribute__((address_space(1))) void*)g,
      (__attribute__((address_space(3))) void*)l, 16, 0, 0);
}

// ---------------------------------------------------------------------------
// Prep: embed fp32 -> bf16 hi/lo, PRE-SWIZZLED chunk layout (chunk c of row r
// stored at position c^(r&7)); fused e2[m] = sum_k embed[m][k]^2.
// One thread per 16B chunk: 4096 rows x 32 chunks, grid 512 x 256.
// ---------------------------------------------------------------------------
__global__ __launch_bounds__(256) void vq_prep_kernel(
    const float* __restrict__ embed, char* __restrict__ ehi,
    char* __restrict__ elo, float* __restrict__ e2) {
  const int id = blockIdx.x * 256 + threadIdx.x;
  const int row = id >> 5;
  const int c = id & 31;
  const float* ep = embed + (size_t)row * DDIM + c * 8;
  const float4 f0 = *(const float4*)(ep);
  const float4 f1 = *(const float4*)(ep + 4);
  float f[8] = {f0.x, f0.y, f0.z, f0.w, f1.x, f1.y, f1.z, f1.w};
  bf16x8 h, l;
  cvt8(f, h, l);
  const size_t off = (size_t)row * 512 + (size_t)(((c ^ (row & 7)) * 16));
  *(bf16x8*)(ehi + off) = h;
  *(bf16x8*)(elo + off) = l;
  float s = 0.0f;
  #pragma unroll
  for (int j = 0; j < 8; ++j) s += f[j] * f[j];
  #pragma unroll
  for (int m = 1; m < 32; m <<= 1) s += __shfl_xor(s, m, 64);
  if (c == 0) e2[row] = s;
}

// ---------------------------------------------------------------------------
// Main fused split-bf16 GEMM + running argmin.
// Block: 256 thr (4 waves x 32 rows). Grid: (4 col-splits, 256 row-blocks).
// Each block: 128 rows x 1024 cols, col-tiles of 64, full K=256 accumulated
// via 3 MFMA products (hh + hl + lh) per fragment -> fp32-accurate scores.
// Staging: global_load_lds width=16 from the pre-swizzled ws image (linear
// src, linear LDS dest; swizzle applied on the ds_read side only).
// ---------------------------------------------------------------------------
__global__ __launch_bounds__(256, 2) void vq_main_kernel(
    const float* __restrict__ x, const char* __restrict__ ehi,
    const char* __restrict__ elo, const float* __restrict__ e2,
    float* __restrict__ ws_score, int* __restrict__ ws_idx) {
  __shared__ char lds[65536];  // hi tile [64 rows][512B] @0, lo @32768
  const int tid = threadIdx.x;
  const int lane = tid & 63;
  const int wv = tid >> 6;
  const int split = blockIdx.x;
  const int row0 = blockIdx.y * 128 + wv * 32;
  const int colbase = split * 1024;
  const int l15 = lane & 15;
  const int l4 = lane >> 4;

  // A (x) fragments for full K, split hi/lo: 2 rowfrags x 8 ksteps
  bf16x8 axh[2][8], axl[2][8];
  #pragma unroll
  for (int rf = 0; rf < 2; ++rf) {
    const float* xp = x + (size_t)(row0 + rf * 16 + l15) * DDIM + l4 * 8;
    #pragma unroll
    for (int ks = 0; ks < 8; ++ks) {
      float4 f0 = *(const float4*)(xp + ks * 32);
      float4 f1 = *(const float4*)(xp + ks * 32 + 4);
      float f[8] = {f0.x, f0.y, f0.z, f0.w, f1.x, f1.y, f1.z, f1.w};
      cvt8(f, axh[rf][ks], axl[rf][ks]);
    }
  }

  float minv[2][4];
  int mini[2][4];
  #pragma unroll
  for (int rf = 0; rf < 2; ++rf)
    #pragma unroll
    for (int r = 0; r < 4; ++r) { minv[rf][r] = 3.0e38f; mini[rf][r] = 0; }

  for (int ct = 0; ct < 16; ++ct) {
    __syncthreads();  // previous tile's compute done
    {
      const size_t tb = (size_t)(colbase + ct * 64) * 512 + (size_t)tid * 16;
      const char* ghi = ehi + tb;
      const char* glo = elo + tb;
      #pragma unroll
      for (int i = 0; i < 8; ++i) {
        load_lds16(ghi + i * 4096, lds + tid * 16 + i * 4096);
        load_lds16(glo + i * 4096, lds + 32768 + tid * 16 + i * 4096);
      }
    }
    __syncthreads();  // vmcnt(0) drained by compiler before barrier

    f32x4 acc[2][4];
    #pragma unroll
    for (int rf = 0; rf < 2; ++rf)
      #pragma unroll
      for (int cf = 0; cf < 4; ++cf) {
        f32x4 z = {0.0f, 0.0f, 0.0f, 0.0f};
        acc[rf][cf] = z;
      }

    #pragma unroll
    for (int ks = 0; ks < 8; ++ks) {
      bf16x8 bh[4], bl[4];
      #pragma unroll
      for (int cf = 0; cf < 4; ++cf) {
        const int brow = cf * 16 + l15;
        const int off = brow * 512 + (((ks * 4 + l4) ^ (brow & 7)) * 16);
        bh[cf] = *(const bf16x8*)(lds + off);
        bl[cf] = *(const bf16x8*)(lds + 32768 + off);
      }
      #pragma unroll
      for (int rf = 0; rf < 2; ++rf)
        #pragma unroll
        for (int cf = 0; cf < 4; ++cf) {
          f32x4 a = acc[rf][cf];
          a = __builtin_amdgcn_mfma_f32_16x16x32_bf16(axh[rf][ks], bh[cf], a, 0, 0, 0);
          a = __builtin_amdgcn_mfma_f32_16x16x32_bf16(axh[rf][ks], bl[cf], a, 0, 0, 0);
          a = __builtin_amdgcn_mfma_f32_16x16x32_bf16(axl[rf][ks], bh[cf], a, 0, 0, 0);
          acc[rf][cf] = a;
        }
    }

    // score = e2[col] - 2*dot ; running argmin (cols increase -> strict < keeps first)
    #pragma unroll
    for (int cf = 0; cf < 4; ++cf) {
      const int col = colbase + ct * 64 + cf * 16 + l15;
      const float ee = e2[col];
      #pragma unroll
      for (int rf = 0; rf < 2; ++rf)
        #pragma unroll
        for (int r = 0; r < 4; ++r) {
          const float s = ee - 2.0f * acc[rf][cf][r];
          if (s < minv[rf][r]) { minv[rf][r] = s; mini[rf][r] = col; }
        }
    }
  }

  // cross-lane (16 lanes share a row) lexicographic argmin reduce
  #pragma unroll
  for (int rf = 0; rf < 2; ++rf)
    #pragma unroll
    for (int r = 0; r < 4; ++r) {
      float s = minv[rf][r];
      int c = mini[rf][r];
      #pragma unroll
      for (int m = 1; m < 16; m <<= 1) {
        const float os = __shfl_xor(s, m, 64);
        const int oc = __shfl_xor(c, m, 64);
        if (os < s || (os == s && oc < c)) { s = os; c = oc; }
      }
      if (l15 == 0) {
        const int row = row0 + rf * 16 + l4 * 4 + r;
        ws_score[row * 4 + split] = s;
        ws_idx[row * 4 + split] = c;
      }
    }
}

// ---------------------------------------------------------------------------
// Merge 4 col-splits per row -> final idx; histogram; idx-as-float output
// ---------------------------------------------------------------------------
__global__ void vq_merge_kernel(const float* __restrict__ ws_score,
                                const int* __restrict__ ws_idx,
                                int* __restrict__ minidx,
                                float* __restrict__ counts,
                                float* __restrict__ out_idx) {
  const int row = blockIdx.x * 256 + threadIdx.x;
  float bs = ws_score[row * 4];
  int bc = ws_idx[row * 4];
  #pragma unroll
  for (int s2 = 1; s2 < 4; ++s2) {
    const float s = ws_score[row * 4 + s2];
    const int c = ws_idx[row * 4 + s2];
    if (s < bs || (s == bs && c < bc)) { bs = s; bc = c; }
  }
  minidx[row] = bc;
  out_idx[row] = (float)bc;
  atomicAdd(&counts[bc], 1.0f);
}

// ---------------------------------------------------------------------------
// Gather quantized = x + (q - x), accumulate loss sum((q-x)^2) in fp64
// ---------------------------------------------------------------------------
__global__ __launch_bounds__(256) void vq_gather_kernel(
    const float* __restrict__ x, const float* __restrict__ embed,
    const int* __restrict__ minidx, float* __restrict__ outq,
    double* __restrict__ loss_acc) {
  const int lane = threadIdx.x & 63;
  const int wv = threadIdx.x >> 6;
  const int row = blockIdx.x * 4 + wv;
  const int idx = minidx[row];
  const float4 q4 = *(const float4*)(embed + (size_t)idx * DDIM + lane * 4);
  const float4 x4 = *(const float4*)(x + (size_t)row * DDIM + lane * 4);
  const float dx = q4.x - x4.x, dy = q4.y - x4.y, dz = q4.z - x4.z, dw = q4.w - x4.w;
  float4 o;
  o.x = x4.x + dx; o.y = x4.y + dy; o.z = x4.z + dz; o.w = x4.w + dw;
  *(float4*)(outq + (size_t)row * DDIM + lane * 4) = o;
  double ss = (double)(dx * dx) + (double)(dy * dy) + (double)(dz * dz) + (double)(dw * dw);
  #pragma unroll
  for (int m = 1; m < 64; m <<= 1) ss += __shfl_xor(ss, m, 64);
  if (lane == 0) atomicAdd(loss_acc, ss);
}

// ---------------------------------------------------------------------------
// Finalize: loss scalar + perplexity
// ---------------------------------------------------------------------------
__global__ void vq_fin_kernel(const float* __restrict__ counts,
                              const double* __restrict__ loss_acc,
                              float* __restrict__ out) {
  __shared__ double sh[256];
  double h = 0.0;
  for (int i = threadIdx.x; i < MCB; i += 256) {
    const float p = counts[i] * (1.0f / 32768.0f);
    h += (double)(p * logf(p + 1e-10f));
  }
  sh[threadIdx.x] = h;
  __syncthreads();
  for (int s = 128; s > 0; s >>= 1) {
    if (threadIdx.x < s) sh[threadIdx.x] += sh[threadIdx.x + s];
    __syncthreads();
  }
  if (threadIdx.x == 0) {
    const size_t base = (size_t)NTOK * DDIM + NTOK;
    out[base] = (float)(1.25 * loss_acc[0] / (double)((size_t)NTOK * DDIM));
    out[base + 1] = (float)exp(-sh[0]);
  }
}

extern "C" void kernel_launch(void* const* d_in, const int* in_sizes, int n_in,
                              void* d_out, int out_size, void* d_ws, size_t ws_size,
                              hipStream_t stream) {
  const float* x = (const float*)d_in[0];
  const float* embed = (const float*)d_in[1];
  float* out = (float*)d_out;
  char* ws = (char*)d_ws;

  float* ws_score = (float*)(ws);                 // N*4 floats   @ 0x000000
  int* ws_idx = (int*)(ws + 0x80000);             // N*4 ints     @ 0x080000
  int* minidx = (int*)(ws + 0x100000);            // N ints       @ 0x100000
  float* counts = (float*)(ws + 0x120000);        // M floats     @ 0x120000
  double* loss_acc = (double*)(ws + 0x124000);    // 1 double     @ 0x124000
  float* e2 = (float*)(ws + 0x124040);            // M floats     @ 0x124040
  char* ehi = ws + 0x140000;                      // M*512 B      @ 0x140000 (2MB)
  char* elo = ws + 0x340000;                      // M*512 B      @ 0x340000 (2MB)

  hipMemsetAsync(ws + 0x120000, 0, 16384 + 64, stream);  // counts + loss_acc
  hipLaunchKernelGGL(vq_prep_kernel, dim3(512), dim3(256), 0, stream,
                     embed, ehi, elo, e2);
  hipLaunchKernelGGL(vq_main_kernel, dim3(4, 256), dim3(256), 0, stream,
                     x, ehi, elo, e2, ws_score, ws_idx);
  hipLaunchKernelGGL(vq_merge_kernel, dim3(128), dim3(256), 0, stream,
                     ws_score, ws_idx, minidx, counts, out + (size_t)NTOK * DDIM);
  hipLaunchKernelGGL(vq_gather_kernel, dim3(8192), dim3(256), 0, stream,
                     x, embed, minidx, out, loss_acc);
  hipLaunchKernelGGL(vq_fin_kernel, dim3(1), dim3(256), 0, stream,
                     counts, loss_acc, out);
}

// Round 3
// 277.795 us; speedup vs baseline: 2.3375x; 2.3375x over previous
//
#include <hip/hip_runtime.h>
#include <hip/hip_bf16.h>
#include <math.h>

#define NTOK 32768
#define MCB  4096
#define DDIM 256
#define NGATHER 8192   // gather blocks (4 rows each)

typedef __attribute__((ext_vector_type(8))) short bf16x8;
typedef __attribute__((ext_vector_type(4))) float f32x4;

__device__ __forceinline__ unsigned short f2bf_rne(float f) {
  unsigned int u = __float_as_uint(f);
  unsigned int r = u + 0x7FFFu + ((u >> 16) & 1u);
  return (unsigned short)(r >> 16);
}

__device__ __forceinline__ float bf2f(unsigned short h) {
  return __uint_as_float(((unsigned int)h) << 16);
}

__device__ __forceinline__ void cvt8(const float* f, bf16x8& hi, bf16x8& lo) {
  #pragma unroll
  for (int j = 0; j < 8; ++j) {
    unsigned short hs = f2bf_rne(f[j]);
    float lf = f[j] - bf2f(hs);
    hi[j] = (short)hs;
    lo[j] = (short)f2bf_rne(lf);
  }
}

__device__ __forceinline__ void load_lds16(const void* g, void* l) {
  __builtin_amdgcn_global_load_lds(
      (const __attribute__((address_space(1))) void*)g,
      (__attribute__((address_space(3))) void*)l, 16, 0, 0);
}

// ---------------------------------------------------------------------------
// Prep: embed fp32 -> bf16 hi/lo, PRE-SWIZZLED chunk layout (chunk c of row r
// stored at position c^(r&7)); fused e2[m] = sum_k embed[m][k]^2.
// ---------------------------------------------------------------------------
__global__ __launch_bounds__(256) void vq_prep_kernel(
    const float* __restrict__ embed, char* __restrict__ ehi,
    char* __restrict__ elo, float* __restrict__ e2) {
  const int id = blockIdx.x * 256 + threadIdx.x;
  const int row = id >> 5;
  const int c = id & 31;
  const float* ep = embed + (size_t)row * DDIM + c * 8;
  const float4 f0 = *(const float4*)(ep);
  const float4 f1 = *(const float4*)(ep + 4);
  float f[8] = {f0.x, f0.y, f0.z, f0.w, f1.x, f1.y, f1.z, f1.w};
  bf16x8 h, l;
  cvt8(f, h, l);
  const size_t off = (size_t)row * 512 + (size_t)(((c ^ (row & 7)) * 16));
  *(bf16x8*)(ehi + off) = h;
  *(bf16x8*)(elo + off) = l;
  float s = 0.0f;
  #pragma unroll
  for (int j = 0; j < 8; ++j) s += f[j] * f[j];
  #pragma unroll
  for (int m = 1; m < 32; m <<= 1) s += __shfl_xor(s, m, 64);
  if (c == 0) e2[row] = s;
}

// ---------------------------------------------------------------------------
// Main fused split-bf16 GEMM + running argmin (unchanged from round 1).
// ---------------------------------------------------------------------------
__global__ __launch_bounds__(256, 2) void vq_main_kernel(
    const float* __restrict__ x, const char* __restrict__ ehi,
    const char* __restrict__ elo, const float* __restrict__ e2,
    float* __restrict__ ws_score, int* __restrict__ ws_idx) {
  __shared__ char lds[65536];  // hi tile [64 rows][512B] @0, lo @32768
  const int tid = threadIdx.x;
  const int lane = tid & 63;
  const int wv = tid >> 6;
  const int split = blockIdx.x;
  const int row0 = blockIdx.y * 128 + wv * 32;
  const int colbase = split * 1024;
  const int l15 = lane & 15;
  const int l4 = lane >> 4;

  bf16x8 axh[2][8], axl[2][8];
  #pragma unroll
  for (int rf = 0; rf < 2; ++rf) {
    const float* xp = x + (size_t)(row0 + rf * 16 + l15) * DDIM + l4 * 8;
    #pragma unroll
    for (int ks = 0; ks < 8; ++ks) {
      float4 f0 = *(const float4*)(xp + ks * 32);
      float4 f1 = *(const float4*)(xp + ks * 32 + 4);
      float f[8] = {f0.x, f0.y, f0.z, f0.w, f1.x, f1.y, f1.z, f1.w};
      cvt8(f, axh[rf][ks], axl[rf][ks]);
    }
  }

  float minv[2][4];
  int mini[2][4];
  #pragma unroll
  for (int rf = 0; rf < 2; ++rf)
    #pragma unroll
    for (int r = 0; r < 4; ++r) { minv[rf][r] = 3.0e38f; mini[rf][r] = 0; }

  for (int ct = 0; ct < 16; ++ct) {
    __syncthreads();
    {
      const size_t tb = (size_t)(colbase + ct * 64) * 512 + (size_t)tid * 16;
      const char* ghi = ehi + tb;
      const char* glo = elo + tb;
      #pragma unroll
      for (int i = 0; i < 8; ++i) {
        load_lds16(ghi + i * 4096, lds + tid * 16 + i * 4096);
        load_lds16(glo + i * 4096, lds + 32768 + tid * 16 + i * 4096);
      }
    }
    __syncthreads();

    f32x4 acc[2][4];
    #pragma unroll
    for (int rf = 0; rf < 2; ++rf)
      #pragma unroll
      for (int cf = 0; cf < 4; ++cf) {
        f32x4 z = {0.0f, 0.0f, 0.0f, 0.0f};
        acc[rf][cf] = z;
      }

    #pragma unroll
    for (int ks = 0; ks < 8; ++ks) {
      bf16x8 bh[4], bl[4];
      #pragma unroll
      for (int cf = 0; cf < 4; ++cf) {
        const int brow = cf * 16 + l15;
        const int off = brow * 512 + (((ks * 4 + l4) ^ (brow & 7)) * 16);
        bh[cf] = *(const bf16x8*)(lds + off);
        bl[cf] = *(const bf16x8*)(lds + 32768 + off);
      }
      #pragma unroll
      for (int rf = 0; rf < 2; ++rf)
        #pragma unroll
        for (int cf = 0; cf < 4; ++cf) {
          f32x4 a = acc[rf][cf];
          a = __builtin_amdgcn_mfma_f32_16x16x32_bf16(axh[rf][ks], bh[cf], a, 0, 0, 0);
          a = __builtin_amdgcn_mfma_f32_16x16x32_bf16(axh[rf][ks], bl[cf], a, 0, 0, 0);
          a = __builtin_amdgcn_mfma_f32_16x16x32_bf16(axl[rf][ks], bh[cf], a, 0, 0, 0);
          acc[rf][cf] = a;
        }
    }

    #pragma unroll
    for (int cf = 0; cf < 4; ++cf) {
      const int col = colbase + ct * 64 + cf * 16 + l15;
      const float ee = e2[col];
      #pragma unroll
      for (int rf = 0; rf < 2; ++rf)
        #pragma unroll
        for (int r = 0; r < 4; ++r) {
          const float s = ee - 2.0f * acc[rf][cf][r];
          if (s < minv[rf][r]) { minv[rf][r] = s; mini[rf][r] = col; }
        }
    }
  }

  #pragma unroll
  for (int rf = 0; rf < 2; ++rf)
    #pragma unroll
    for (int r = 0; r < 4; ++r) {
      float s = minv[rf][r];
      int c = mini[rf][r];
      #pragma unroll
      for (int m = 1; m < 16; m <<= 1) {
        const float os = __shfl_xor(s, m, 64);
        const int oc = __shfl_xor(c, m, 64);
        if (os < s || (os == s && oc < c)) { s = os; c = oc; }
      }
      if (l15 == 0) {
        const int row = row0 + rf * 16 + l4 * 4 + r;
        ws_score[row * 4 + split] = s;
        ws_idx[row * 4 + split] = c;
      }
    }
}

// ---------------------------------------------------------------------------
// Merge 4 col-splits per row -> final idx; histogram; idx-as-float output
// ---------------------------------------------------------------------------
__global__ void vq_merge_kernel(const float* __restrict__ ws_score,
                                const int* __restrict__ ws_idx,
                                int* __restrict__ minidx,
                                float* __restrict__ counts,
                                float* __restrict__ out_idx) {
  const int row = blockIdx.x * 256 + threadIdx.x;
  float bs = ws_score[row * 4];
  int bc = ws_idx[row * 4];
  #pragma unroll
  for (int s2 = 1; s2 < 4; ++s2) {
    const float s = ws_score[row * 4 + s2];
    const int c = ws_idx[row * 4 + s2];
    if (s < bs || (s == bs && c < bc)) { bs = s; bc = c; }
  }
  minidx[row] = bc;
  out_idx[row] = (float)bc;
  atomicAdd(&counts[bc], 1.0f);
}

// ---------------------------------------------------------------------------
// Gather quantized = x + (q - x); per-block fp64 partial of sum((q-x)^2).
// NO global atomics (round-2 fix: single-address fp64 atomicAdd serialized
// 32768 waves -> 398 us; partials array removes it entirely).
// ---------------------------------------------------------------------------
__global__ __launch_bounds__(256) void vq_gather_kernel(
    const float* __restrict__ x, const float* __restrict__ embed,
    const int* __restrict__ minidx, float* __restrict__ outq,
    double* __restrict__ partials) {
  __shared__ double sh[4];
  const int lane = threadIdx.x & 63;
  const int wv = threadIdx.x >> 6;
  const int row = blockIdx.x * 4 + wv;
  const int idx = minidx[row];
  const float4 q4 = *(const float4*)(embed + (size_t)idx * DDIM + lane * 4);
  const float4 x4 = *(const float4*)(x + (size_t)row * DDIM + lane * 4);
  const float dx = q4.x - x4.x, dy = q4.y - x4.y, dz = q4.z - x4.z, dw = q4.w - x4.w;
  float4 o;
  o.x = x4.x + dx; o.y = x4.y + dy; o.z = x4.z + dz; o.w = x4.w + dw;
  *(float4*)(outq + (size_t)row * DDIM + lane * 4) = o;
  double ss = (double)(dx * dx) + (double)(dy * dy) + (double)(dz * dz) + (double)(dw * dw);
  #pragma unroll
  for (int m = 1; m < 64; m <<= 1) ss += __shfl_xor(ss, m, 64);
  if (lane == 0) sh[wv] = ss;
  __syncthreads();
  if (threadIdx.x == 0) partials[blockIdx.x] = sh[0] + sh[1] + sh[2] + sh[3];
}

// ---------------------------------------------------------------------------
// Finalize: sum loss partials + entropy -> loss scalar + perplexity
// ---------------------------------------------------------------------------
__global__ void vq_fin_kernel(const float* __restrict__ counts,
                              const double* __restrict__ partials,
                              float* __restrict__ out) {
  __shared__ double sh[256];
  __shared__ double sl[256];
  double h = 0.0;
  for (int i = threadIdx.x; i < MCB; i += 256) {
    const float p = counts[i] * (1.0f / 32768.0f);
    h += (double)(p * logf(p + 1e-10f));
  }
  double ls = 0.0;
  for (int i = threadIdx.x; i < NGATHER; i += 256) ls += partials[i];
  sh[threadIdx.x] = h;
  sl[threadIdx.x] = ls;
  __syncthreads();
  for (int s = 128; s > 0; s >>= 1) {
    if (threadIdx.x < s) {
      sh[threadIdx.x] += sh[threadIdx.x + s];
      sl[threadIdx.x] += sl[threadIdx.x + s];
    }
    __syncthreads();
  }
  if (threadIdx.x == 0) {
    const size_t base = (size_t)NTOK * DDIM + NTOK;
    out[base] = (float)(1.25 * sl[0] / (double)((size_t)NTOK * DDIM));
    out[base + 1] = (float)exp(-sh[0]);
  }
}

extern "C" void kernel_launch(void* const* d_in, const int* in_sizes, int n_in,
                              void* d_out, int out_size, void* d_ws, size_t ws_size,
                              hipStream_t stream) {
  const float* x = (const float*)d_in[0];
  const float* embed = (const float*)d_in[1];
  float* out = (float*)d_out;
  char* ws = (char*)d_ws;

  float* ws_score = (float*)(ws);                 // N*4 floats   @ 0x000000
  int* ws_idx = (int*)(ws + 0x80000);             // N*4 ints     @ 0x080000
  int* minidx = (int*)(ws + 0x100000);            // N ints       @ 0x100000
  float* counts = (float*)(ws + 0x120000);        // M floats     @ 0x120000
  double* partials = (double*)(ws + 0x128000);    // 8192 doubles @ 0x128000 (64KB)
  float* e2 = (float*)(ws + 0x138000);            // M floats     @ 0x138000
  char* ehi = ws + 0x140000;                      // M*512 B      @ 0x140000 (2MB)
  char* elo = ws + 0x340000;                      // M*512 B      @ 0x340000 (2MB)

  hipMemsetAsync(ws + 0x120000, 0, 16384, stream);  // counts
  hipLaunchKernelGGL(vq_prep_kernel, dim3(512), dim3(256), 0, stream,
                     embed, ehi, elo, e2);
  hipLaunchKernelGGL(vq_main_kernel, dim3(4, 256), dim3(256), 0, stream,
                     x, ehi, elo, e2, ws_score, ws_idx);
  hipLaunchKernelGGL(vq_merge_kernel, dim3(128), dim3(256), 0, stream,
                     ws_score, ws_idx, minidx, counts, out + (size_t)NTOK * DDIM);
  hipLaunchKernelGGL(vq_gather_kernel, dim3(NGATHER), dim3(256), 0, stream,
                     x, embed, minidx, out, partials);
  hipLaunchKernelGGL(vq_fin_kernel, dim3(1), dim3(256), 0, stream,
                     counts, partials, out);
}

// Round 4
// 266.785 us; speedup vs baseline: 2.4340x; 1.0413x over previous
//
#include <hip/hip_runtime.h>
#include <hip/hip_bf16.h>
#include <math.h>

#define NTOK 32768
#define MCB  4096
#define DDIM 256
#define NGATHER 8192   // gather blocks (4 rows each)

typedef __attribute__((ext_vector_type(8))) short bf16x8;
typedef __attribute__((ext_vector_type(4))) float f32x4;

__device__ __forceinline__ unsigned short f2bf_rne(float f) {
  unsigned int u = __float_as_uint(f);
  unsigned int r = u + 0x7FFFu + ((u >> 16) & 1u);
  return (unsigned short)(r >> 16);
}

__device__ __forceinline__ float bf2f(unsigned short h) {
  return __uint_as_float(((unsigned int)h) << 16);
}

__device__ __forceinline__ void cvt8(const float* f, bf16x8& hi, bf16x8& lo) {
  #pragma unroll
  for (int j = 0; j < 8; ++j) {
    unsigned short hs = f2bf_rne(f[j]);
    float lf = f[j] - bf2f(hs);
    hi[j] = (short)hs;
    lo[j] = (short)f2bf_rne(lf);
  }
}

__device__ __forceinline__ void load_lds16(const void* g, void* l) {
  __builtin_amdgcn_global_load_lds(
      (const __attribute__((address_space(1))) void*)g,
      (__attribute__((address_space(3))) void*)l, 16, 0, 0);
}

// ---------------------------------------------------------------------------
// Prep: embed fp32 -> bf16 hi/lo, PRE-SWIZZLED chunk layout (chunk c of row r
// stored at position c^(r&7)); fused e2[m] = sum_k embed[m][k]^2.
// ---------------------------------------------------------------------------
__global__ __launch_bounds__(256) void vq_prep_kernel(
    const float* __restrict__ embed, char* __restrict__ ehi,
    char* __restrict__ elo, float* __restrict__ e2) {
  const int id = blockIdx.x * 256 + threadIdx.x;
  const int row = id >> 5;
  const int c = id & 31;
  const float* ep = embed + (size_t)row * DDIM + c * 8;
  const float4 f0 = *(const float4*)(ep);
  const float4 f1 = *(const float4*)(ep + 4);
  float f[8] = {f0.x, f0.y, f0.z, f0.w, f1.x, f1.y, f1.z, f1.w};
  bf16x8 h, l;
  cvt8(f, h, l);
  const size_t off = (size_t)row * 512 + (size_t)(((c ^ (row & 7)) * 16));
  *(bf16x8*)(ehi + off) = h;
  *(bf16x8*)(elo + off) = l;
  float s = 0.0f;
  #pragma unroll
  for (int j = 0; j < 8; ++j) s += f[j] * f[j];
  #pragma unroll
  for (int m = 1; m < 32; m <<= 1) s += __shfl_xor(s, m, 64);
  if (c == 0) e2[row] = s;
}

// ---------------------------------------------------------------------------
// Main fused split-bf16 GEMM + running argmin.
// Round-3 change: double-buffered LDS (2 x 32KB, 32-col tiles) with the
// "minimum 2-phase" pipeline: STAGE(next) issued BEFORE compute(cur); the
// only drain is the vmcnt(0) the compiler emits at the end-of-iter barrier,
// so staging latency hides under ~900 cy of MFMA instead of stalling.
// ---------------------------------------------------------------------------
__global__ __launch_bounds__(256, 2) void vq_main_kernel(
    const float* __restrict__ x, const char* __restrict__ ehi,
    const char* __restrict__ elo, const float* __restrict__ e2,
    float* __restrict__ ws_score, int* __restrict__ ws_idx) {
  // buf c: hi tile [32 rows][512B] @ c*32768, lo @ c*32768+16384
  __shared__ char lds[65536];
  const int tid = threadIdx.x;
  const int lane = tid & 63;
  const int wv = tid >> 6;
  const int split = blockIdx.x;
  const int row0 = blockIdx.y * 128 + wv * 32;
  const int colbase = split * 1024;
  const int l15 = lane & 15;
  const int l4 = lane >> 4;

  // A (x) fragments for full K, split hi/lo: 2 rowfrags x 8 ksteps
  bf16x8 axh[2][8], axl[2][8];
  #pragma unroll
  for (int rf = 0; rf < 2; ++rf) {
    const float* xp = x + (size_t)(row0 + rf * 16 + l15) * DDIM + l4 * 8;
    #pragma unroll
    for (int ks = 0; ks < 8; ++ks) {
      float4 f0 = *(const float4*)(xp + ks * 32);
      float4 f1 = *(const float4*)(xp + ks * 32 + 4);
      float f[8] = {f0.x, f0.y, f0.z, f0.w, f1.x, f1.y, f1.z, f1.w};
      cvt8(f, axh[rf][ks], axl[rf][ks]);
    }
  }

  float minv[2][4];
  int mini[2][4];
  #pragma unroll
  for (int rf = 0; rf < 2; ++rf)
    #pragma unroll
    for (int r = 0; r < 4; ++r) { minv[rf][r] = 3.0e38f; mini[rf][r] = 0; }

  // stage a 32-col tile (16KB hi + 16KB lo) into buffer c
  auto stage = [&](int ct, int c) {
    const size_t tb = (size_t)(colbase + ct * 32) * 512 + (size_t)tid * 16;
    const char* ghi = ehi + tb;
    const char* glo = elo + tb;
    char* dst = lds + c * 32768 + tid * 16;
    #pragma unroll
    for (int i = 0; i < 4; ++i) {
      load_lds16(ghi + i * 4096, dst + i * 4096);
      load_lds16(glo + i * 4096, dst + 16384 + i * 4096);
    }
  };

  stage(0, 0);
  __syncthreads();  // compiler emits vmcnt(0) drain before barrier

  for (int ct = 0; ct < 32; ++ct) {
    const int cur = ct & 1;
    // issue next tile's staging FIRST -- overlaps with compute below
    if (ct < 31) stage(ct + 1, cur ^ 1);

    const char* base = lds + cur * 32768;
    f32x4 acc[2][2];
    #pragma unroll
    for (int rf = 0; rf < 2; ++rf)
      #pragma unroll
      for (int cf = 0; cf < 2; ++cf) {
        f32x4 z = {0.0f, 0.0f, 0.0f, 0.0f};
        acc[rf][cf] = z;
      }

    #pragma unroll
    for (int ks = 0; ks < 8; ++ks) {
      bf16x8 bh[2], bl[2];
      #pragma unroll
      for (int cf = 0; cf < 2; ++cf) {
        const int brow = cf * 16 + l15;
        const int off = brow * 512 + (((ks * 4 + l4) ^ (brow & 7)) * 16);
        bh[cf] = *(const bf16x8*)(base + off);
        bl[cf] = *(const bf16x8*)(base + 16384 + off);
      }
      #pragma unroll
      for (int rf = 0; rf < 2; ++rf)
        #pragma unroll
        for (int cf = 0; cf < 2; ++cf) {
          f32x4 a = acc[rf][cf];
          a = __builtin_amdgcn_mfma_f32_16x16x32_bf16(axh[rf][ks], bh[cf], a, 0, 0, 0);
          a = __builtin_amdgcn_mfma_f32_16x16x32_bf16(axh[rf][ks], bl[cf], a, 0, 0, 0);
          a = __builtin_amdgcn_mfma_f32_16x16x32_bf16(axl[rf][ks], bh[cf], a, 0, 0, 0);
          acc[rf][cf] = a;
        }
    }

    // score = e2[col] - 2*dot ; running argmin (cols increase -> strict < keeps first)
    #pragma unroll
    for (int cf = 0; cf < 2; ++cf) {
      const int col = colbase + ct * 32 + cf * 16 + l15;
      const float ee = e2[col];
      #pragma unroll
      for (int rf = 0; rf < 2; ++rf)
        #pragma unroll
        for (int r = 0; r < 4; ++r) {
          const float s = ee - 2.0f * acc[rf][cf][r];
          if (s < minv[rf][r]) { minv[rf][r] = s; mini[rf][r] = col; }
        }
    }

    __syncthreads();  // drains vmcnt(0): next tile ready; cur free to overwrite
  }

  // cross-lane (16 lanes share a row) lexicographic argmin reduce
  #pragma unroll
  for (int rf = 0; rf < 2; ++rf)
    #pragma unroll
    for (int r = 0; r < 4; ++r) {
      float s = minv[rf][r];
      int c = mini[rf][r];
      #pragma unroll
      for (int m = 1; m < 16; m <<= 1) {
        const float os = __shfl_xor(s, m, 64);
        const int oc = __shfl_xor(c, m, 64);
        if (os < s || (os == s && oc < c)) { s = os; c = oc; }
      }
      if (l15 == 0) {
        const int row = row0 + rf * 16 + l4 * 4 + r;
        ws_score[row * 4 + split] = s;
        ws_idx[row * 4 + split] = c;
      }
    }
}

// ---------------------------------------------------------------------------
// Merge 4 col-splits per row -> final idx; histogram; idx-as-float output
// ---------------------------------------------------------------------------
__global__ void vq_merge_kernel(const float* __restrict__ ws_score,
                                const int* __restrict__ ws_idx,
                                int* __restrict__ minidx,
                                float* __restrict__ counts,
                                float* __restrict__ out_idx) {
  const int row = blockIdx.x * 256 + threadIdx.x;
  float bs = ws_score[row * 4];
  int bc = ws_idx[row * 4];
  #pragma unroll
  for (int s2 = 1; s2 < 4; ++s2) {
    const float s = ws_score[row * 4 + s2];
    const int c = ws_idx[row * 4 + s2];
    if (s < bs || (s == bs && c < bc)) { bs = s; bc = c; }
  }
  minidx[row] = bc;
  out_idx[row] = (float)bc;
  atomicAdd(&counts[bc], 1.0f);
}

// ---------------------------------------------------------------------------
// Gather quantized = x + (q - x); per-block fp64 partial of sum((q-x)^2).
// ---------------------------------------------------------------------------
__global__ __launch_bounds__(256) void vq_gather_kernel(
    const float* __restrict__ x, const float* __restrict__ embed,
    const int* __restrict__ minidx, float* __restrict__ outq,
    double* __restrict__ partials) {
  __shared__ double sh[4];
  const int lane = threadIdx.x & 63;
  const int wv = threadIdx.x >> 6;
  const int row = blockIdx.x * 4 + wv;
  const int idx = minidx[row];
  const float4 q4 = *(const float4*)(embed + (size_t)idx * DDIM + lane * 4);
  const float4 x4 = *(const float4*)(x + (size_t)row * DDIM + lane * 4);
  const float dx = q4.x - x4.x, dy = q4.y - x4.y, dz = q4.z - x4.z, dw = q4.w - x4.w;
  float4 o;
  o.x = x4.x + dx; o.y = x4.y + dy; o.z = x4.z + dz; o.w = x4.w + dw;
  *(float4*)(outq + (size_t)row * DDIM + lane * 4) = o;
  double ss = (double)(dx * dx) + (double)(dy * dy) + (double)(dz * dz) + (double)(dw * dw);
  #pragma unroll
  for (int m = 1; m < 64; m <<= 1) ss += __shfl_xor(ss, m, 64);
  if (lane == 0) sh[wv] = ss;
  __syncthreads();
  if (threadIdx.x == 0) partials[blockIdx.x] = sh[0] + sh[1] + sh[2] + sh[3];
}

// ---------------------------------------------------------------------------
// Finalize: sum loss partials + entropy -> loss scalar + perplexity
// ---------------------------------------------------------------------------
__global__ void vq_fin_kernel(const float* __restrict__ counts,
                              const double* __restrict__ partials,
                              float* __restrict__ out) {
  __shared__ double sh[256];
  __shared__ double sl[256];
  double h = 0.0;
  for (int i = threadIdx.x; i < MCB; i += 256) {
    const float p = counts[i] * (1.0f / 32768.0f);
    h += (double)(p * logf(p + 1e-10f));
  }
  double ls = 0.0;
  for (int i = threadIdx.x; i < NGATHER; i += 256) ls += partials[i];
  sh[threadIdx.x] = h;
  sl[threadIdx.x] = ls;
  __syncthreads();
  for (int s = 128; s > 0; s >>= 1) {
    if (threadIdx.x < s) {
      sh[threadIdx.x] += sh[threadIdx.x + s];
      sl[threadIdx.x] += sl[threadIdx.x + s];
    }
    __syncthreads();
  }
  if (threadIdx.x == 0) {
    const size_t base = (size_t)NTOK * DDIM + NTOK;
    out[base] = (float)(1.25 * sl[0] / (double)((size_t)NTOK * DDIM));
    out[base + 1] = (float)exp(-sh[0]);
  }
}

extern "C" void kernel_launch(void* const* d_in, const int* in_sizes, int n_in,
                              void* d_out, int out_size, void* d_ws, size_t ws_size,
                              hipStream_t stream) {
  const float* x = (const float*)d_in[0];
  const float* embed = (const float*)d_in[1];
  float* out = (float*)d_out;
  char* ws = (char*)d_ws;

  float* ws_score = (float*)(ws);                 // N*4 floats   @ 0x000000
  int* ws_idx = (int*)(ws + 0x80000);             // N*4 ints     @ 0x080000
  int* minidx = (int*)(ws + 0x100000);            // N ints       @ 0x100000
  float* counts = (float*)(ws + 0x120000);        // M floats     @ 0x120000
  double* partials = (double*)(ws + 0x128000);    // 8192 doubles @ 0x128000 (64KB)
  float* e2 = (float*)(ws + 0x138000);            // M floats     @ 0x138000
  char* ehi = ws + 0x140000;                      // M*512 B      @ 0x140000 (2MB)
  char* elo = ws + 0x340000;                      // M*512 B      @ 0x340000 (2MB)

  hipMemsetAsync(ws + 0x120000, 0, 16384, stream);  // counts
  hipLaunchKernelGGL(vq_prep_kernel, dim3(512), dim3(256), 0, stream,
                     embed, ehi, elo, e2);
  hipLaunchKernelGGL(vq_main_kernel, dim3(4, 256), dim3(256), 0, stream,
                     x, ehi, elo, e2, ws_score, ws_idx);
  hipLaunchKernelGGL(vq_merge_kernel, dim3(128), dim3(256), 0, stream,
                     ws_score, ws_idx, minidx, counts, out + (size_t)NTOK * DDIM);
  hipLaunchKernelGGL(vq_gather_kernel, dim3(NGATHER), dim3(256), 0, stream,
                     x, embed, minidx, out, partials);
  hipLaunchKernelGGL(vq_fin_kernel, dim3(1), dim3(256), 0, stream,
                     counts, partials, out);
}